// Round 7
// baseline (679.528 us; speedup 1.0000x reference)
//
#include <hip/hip_runtime.h>
#include <hip/hip_bf16.h>
#include <math.h>

typedef __attribute__((ext_vector_type(4))) float f32x4;
typedef __attribute__((ext_vector_type(8))) short s16x8;

#define LOG2E 1.4426950408889634f
#define LN2f  0.6931471805599453f
#define INV_E 0.36787944117144233f

__device__ __forceinline__ short bfc(float x) {
  unsigned u = __float_as_uint(x);
  unsigned r = u + 0x7fffu + ((u >> 16) & 1u);   // RNE to bf16
  return (short)(r >> 16);
}

__device__ __forceinline__ unsigned pk2(float x, float y) {
  union { __hip_bfloat162 h; unsigned u; } c;
  c.h = __float22bfloat162_rn(make_float2(x, y));  // v_cvt_pk_bf16_f32
  return c.u;
}

__device__ __forceinline__ float bperm(float v, int byte_addr) {
  return __int_as_float(__builtin_amdgcn_ds_bpermute(byte_addr, __float_as_int(v)));
}

__device__ __forceinline__ float rdlane(float v, int lane) {
  return __int_as_float(__builtin_amdgcn_readlane(__float_as_int(v), lane));
}

__device__ __forceinline__ float pick5(int j, float x0, float x1, float x2,
                                       float x3, float x4) {
  float v = x0;
  if (j == 1) v = x1;
  if (j == 2) v = x2;
  if (j == 3) v = x3;
  if (j == 4) v = x4;
  return v;
}

// async global -> LDS, 16B/lane: LDS dest = wave-uniform base + lane*16,
// global src per-lane [m03/m97/m104/m173]
__device__ __forceinline__ void gload_lds16(const float* g, float* l) {
  __builtin_amdgcn_global_load_lds(
      (const __attribute__((address_space(1))) unsigned int*)g,
      (__attribute__((address_space(3))) unsigned int*)l, 16, 0, 0);
}

// ---------------------------------------------------------------------------
// Kernel 0: W (V x D fp32) -> Wb (64 x D bf16), rows >= V zero-filled.
// Also zeroes the producer/consumer flags.
// ---------------------------------------------------------------------------
__global__ void conv_w(const float* __restrict__ W, short* __restrict__ Wb,
                       int V, int D, int* __restrict__ flags, int nflags) {
  int idx = blockIdx.x * blockDim.x + threadIdx.x;
  if (idx < nflags) flags[idx] = 0;
  if (idx >= 64 * D) return;
  int row = idx / D, col = idx - row * D;
  Wb[idx] = (row < V) ? bfc(W[(size_t)row * D + col]) : (short)0;
}

// ---------------------------------------------------------------------------
// Fused kernel v7. Producer byte-identical to v6 (per-wave LDS A-panels,
// 44.5us/tile, 1.47 TB/s). r6 counters: fused 409 = 44 (chunk-0) + 333 DP;
// DP = single wave at 390 cyc/step, latency+issue bound (~100 instr/pair,
// no co-resident wave to hide stalls).
// v7 consumer: ONE SEQUENCE SPLIT ACROSS 2 WAVES (4 token-states + 1
// overlap star per lane; 128 lanes cover 513 states). Per-pair updates
// 56->32 instrs, gathers 9->5 bperm, renorm 9->5 ldexp. Single cross-wave
// boundary (wave1 lane0 <- wave0 lane63: b1,b2,b3,eps) via 2-slot
// ping-pong LDS + ONE barrier/pair (slot parity makes the next overwrite
// race-free by program order). Waves 2,3 = barrier-count-matched escort.
// Sync with producer unchanged: per-(b,c) flag RELEASE; relaxed agent-scope
// poll + one acquire fence per chunk crossing.
// ---------------------------------------------------------------------------
__global__ __launch_bounds__(256) void fused_gemm_star(
    const float* __restrict__ feat, const short* __restrict__ Wb,
    const float* __restrict__ bias, float* __restrict__ pt,
    int* __restrict__ flags,
    const int* __restrict__ targets, const int* __restrict__ in_len,
    const int* __restrict__ tgt_len, float* __restrict__ partial,
    int nrows, int D, int V, int T, int S, int B, int CPB) {

  // per-wave A panels: [wave][32 rows][128 f32] = 64 KB total
  // consumer reuses: [0..16) = boundary ping-pong (2 slots x 8 f32),
  //                  [16..20) = final-reduce scratch
  __shared__ __align__(16) float Ap[4 * 32 * 128];

  if ((int)blockIdx.x >= B) {
    // ======================= persistent producer ==========================
    const int NPROD = gridDim.x - B;
    const int NTILES = B * CPB;
    const int lane = threadIdx.x & 63;
    const int wave = threadIdx.x >> 6;
    const int m_lo = lane & 15;
    const int q = lane >> 4;
    float* wpan = Ap + wave * 32 * 128;            // this wave's panel
    char* wpanb = (char*)wpan;

    for (int i = blockIdx.x - B; i < NTILES; i += NPROD) {
      const int c = i / B;
      const int b = i - c * B;
      const int tc0 = c * 128;
      const int rlen = (T - tc0 < 128) ? (T - tc0) : 128;
      const int rowlim = b * T + tc0 + rlen;
      const int rowbase = b * T + tc0 + wave * 32; // this wave's 32 rows

      f32x4 acc[2][4];
      #pragma unroll
      for (int g = 0; g < 2; ++g)
        #pragma unroll
        for (int ni = 0; ni < 4; ++ni) acc[g][ni] = (f32x4){0.f, 0.f, 0.f, 0.f};

      const int xl = (lane & 31) * 16;             // byte off within 512B chunk
      const int rhalf = lane >> 5;                 // 0/1: which row of the pair

      for (int k0 = 0; k0 < D; k0 += 128) {
        // ---- stage: 16 instrs, each = 2 rows x 512B contiguous ----
        #pragma unroll
        for (int ii = 0; ii < 16; ++ii) {
          int rl = ii * 2 + rhalf;                 // local row 0..31
          int grow = rowbase + rl;
          if (grow >= nrows) grow = nrows - 1;     // clamp; stores guarded
          int off = xl ^ ((rl & 7) << 4);          // pre-swizzled source (m173)
          gload_lds16(feat + (size_t)grow * D + k0 + (off >> 2),
                      wpan + ii * 256);            // linear LDS dest (2 rows)
        }
        asm volatile("s_waitcnt vmcnt(0)" ::: "memory");
        // ---- compute 4 x 32-k sub-iters from the panel ----
        const int l0 = m_lo, l1 = m_lo + 16;
        const int sz0 = (l0 & 7) << 4;             // (l1&7)==(l0&7)
        #pragma unroll
        for (int kk = 0; kk < 4; ++kk) {
          int boff = kk * 128 + q * 32;
          float4 lo0 = *(const float4*)(wpanb + l0 * 512 + ((boff) ^ sz0));
          float4 hi0 = *(const float4*)(wpanb + l0 * 512 + ((boff + 16) ^ sz0));
          float4 lo1 = *(const float4*)(wpanb + l1 * 512 + ((boff) ^ sz0));
          float4 hi1 = *(const float4*)(wpanb + l1 * 512 + ((boff + 16) ^ sz0));
          const short* Bpp = Wb + (size_t)m_lo * D + k0 + kk * 32 + q * 8;
          s16x8 b0 = *(const s16x8*)(Bpp);
          s16x8 b1 = *(const s16x8*)(Bpp + (size_t)16 * D);
          s16x8 b2 = *(const s16x8*)(Bpp + (size_t)32 * D);
          s16x8 b3 = *(const s16x8*)(Bpp + (size_t)48 * D);
          union { s16x8 v; unsigned u[4]; } av0, av1;
          av0.u[0] = pk2(lo0.x, lo0.y); av0.u[1] = pk2(lo0.z, lo0.w);
          av0.u[2] = pk2(hi0.x, hi0.y); av0.u[3] = pk2(hi0.z, hi0.w);
          av1.u[0] = pk2(lo1.x, lo1.y); av1.u[1] = pk2(lo1.z, lo1.w);
          av1.u[2] = pk2(hi1.x, hi1.y); av1.u[3] = pk2(hi1.z, hi1.w);
          acc[0][0] = __builtin_amdgcn_mfma_f32_16x16x32_bf16(av0.v, b0, acc[0][0], 0, 0, 0);
          acc[0][1] = __builtin_amdgcn_mfma_f32_16x16x32_bf16(av0.v, b1, acc[0][1], 0, 0, 0);
          acc[0][2] = __builtin_amdgcn_mfma_f32_16x16x32_bf16(av0.v, b2, acc[0][2], 0, 0, 0);
          acc[0][3] = __builtin_amdgcn_mfma_f32_16x16x32_bf16(av0.v, b3, acc[0][3], 0, 0, 0);
          acc[1][0] = __builtin_amdgcn_mfma_f32_16x16x32_bf16(av1.v, b0, acc[1][0], 0, 0, 0);
          acc[1][1] = __builtin_amdgcn_mfma_f32_16x16x32_bf16(av1.v, b1, acc[1][1], 0, 0, 0);
          acc[1][2] = __builtin_amdgcn_mfma_f32_16x16x32_bf16(av1.v, b2, acc[1][2], 0, 0, 0);
          acc[1][3] = __builtin_amdgcn_mfma_f32_16x16x32_bf16(av1.v, b3, acc[1][3], 0, 0, 0);
        }
        // panel reads done in-wave; next stage overwrite is same-wave safe
      }

      float bias_v[4];
      #pragma unroll
      for (int ni = 0; ni < 4; ++ni) {
        int col = ni * 16 + m_lo;
        bias_v[ni] = (col < V) ? bias[col] : 0.f;
      }

      // C/D layout: col = lane&15, row = (lane>>4)*4 + reg   [m89-verified]
      #pragma unroll
      for (int g = 0; g < 2; ++g) {
        #pragma unroll
        for (int r = 0; r < 4; ++r) {
          int grow = rowbase + g * 16 + q * 4 + r;
          float lg[4];
          #pragma unroll
          for (int ni = 0; ni < 4; ++ni) {
            int col = ni * 16 + m_lo;
            lg[ni] = (col < V) ? (acc[g][ni][r] + bias_v[ni]) : -1e30f;
          }
          float m = fmaxf(fmaxf(lg[0], lg[1]), fmaxf(lg[2], lg[3]));
          #pragma unroll
          for (int off = 1; off < 16; off <<= 1) m = fmaxf(m, __shfl_xor(m, off));
          float p[4];
          #pragma unroll
          for (int ni = 0; ni < 4; ++ni) p[ni] = exp2f((lg[ni] - m) * LOG2E);
          float s = (p[0] + p[1]) + (p[2] + p[3]);
          #pragma unroll
          for (int off = 1; off < 16; off <<= 1) s += __shfl_xor(s, off);

          if (grow < rowlim) {
            float* orow = pt + (size_t)grow * 64;
            orow[m_lo] = p[0];
            orow[16 + m_lo] = p[1];
            orow[32 + m_lo] = p[2];
            if (m_lo < 8)       orow[48 + m_lo] = p[3];
            else if (m_lo == 8) orow[56] = logf(s);        // K_t (ln units)
            else if (m_lo == 9) orow[57] = s * INV_E;      // star~ emission
            else                orow[48 + m_lo] = 0.f;     // cols 58..63
          }
        }
      }

      __syncthreads();               // all 4 waves' pt stores issued+drained
      if (threadIdx.x == 0)
        __hip_atomic_store(&flags[b * CPB + c], 1, __ATOMIC_RELEASE,
                           __HIP_MEMORY_SCOPE_AGENT);
    }
    return;
  }

  // ======== consumer: star-CTC DP, one sequence across 2 waves ============
  const int n = blockIdx.x;
  const int wid = threadIdx.x >> 6;
  const int lane = threadIdx.x & 63;
  const int len = in_len[n];

  if (wid >= 2) {
    // escort waves: execute exactly the same barrier sequence as the DP
    // waves (4 per main-loop iter, 1 per tail step, 1 final), then exit.
    int t0e = 1;
    for (; t0e + 8 <= len; t0e += 8) {
      __syncthreads(); __syncthreads(); __syncthreads(); __syncthreads();
    }
    for (int t = t0e; t < len; ++t) __syncthreads();
    __syncthreads();
    return;
  }

  const int g = wid * 64 + lane;                 // global DP lane 0..127
  const float* row = pt + (size_t)n * T * 64;
  const int tl = tgt_len[n];
  const int* tg = targets + (size_t)n * S;
  const int* fl = flags + n * CPB;
  float* bnd = Ap;                               // 2 slots x 8 f32
  float* fin = Ap + 16;                          // vx, ex, vy, ey

  int cdone = -1;
#define WAITC(cc)                                                            \
  do {                                                                       \
    int _c = (cc);                                                           \
    if (cdone < _c) {                                                        \
      while (cdone < _c) {                                                   \
        if (__hip_atomic_load((int*)&fl[cdone + 1], __ATOMIC_RELAXED,        \
                              __HIP_MEMORY_SCOPE_AGENT))                     \
          ++cdone;                                                           \
        else                                                                 \
          __builtin_amdgcn_s_sleep(2);                                       \
      }                                                                      \
      __builtin_amdgcn_fence(__ATOMIC_ACQUIRE, "agent");                     \
    }                                                                        \
  } while (0)

  // lane g holds states 4g..4g+4: b0(star) b1(tok tg[2g]) b2(star)
  // b3(tok tg[2g+1]) b4(star, overlap with lane g+1's b0)
  const int jA = 2 * g, jB = 2 * g + 1;
  const int labA  = (jA < S) ? tg[jA] : 0;
  const int labB  = (jB < S) ? tg[jB] : 0;
  const int labm1 = (g > 0 && jA - 1 < S) ? tg[jA - 1] : 0;  // state 4g-1
  const int labm3 = (g > 0 && jA - 2 < S) ? tg[jA - 2] : 0;  // state 4g-3
  const bool sk1  = (g > 0) && (labA != labm1);
  const bool sk3  = (labB != labA);
  const bool skm1 = (labm1 != labm3);
  const int adA = labA << 2, adB = labB << 2, adm1 = labm1 << 2;

  float b0 = 0, b1v = 0, b2v = 0, b3v = 0, b4v = 0;
  float m1 = 0.f, m2 = 0.f, m3 = 0.f;
  int eps = 0, eL = 0;
  bool act = (g == 0);
  int pp = 0;                                    // boundary slot parity

#define ROWL(t) row[(size_t)(((t) < len) ? (t) : (len - 1)) * 64 + lane]

  WAITC(0);                                      // rows 0..8 live in chunk 0

  // t = 0
  float rc = row[lane];
  {
    float star = rdlane(rc, 57);
    float e1i = bperm(rc, adA);
    if (g == 0) { b0 = star; b1v = e1i; }
  }
  float ksum = rc;

  // prefetch ring: rows 1..8
  float rr0 = ROWL(1), rr1 = ROWL(2), rr2 = ROWL(3), rr3 = ROWL(4);
  float rr4 = ROWL(5), rr5 = ROWL(6), rr6 = ROWL(7), rr7 = ROWL(8);

  // emissions for first pair (t=1,2)
  float es0v = rdlane(rr0, 57);
  float eAa = bperm(rr0, adA), eBa = bperm(rr0, adB), em1a = bperm(rr0, adm1);
  float es1v = rdlane(rr1, 57);
  float eAb = bperm(rr1, adA), eBb = bperm(rr1, adB);

#define RENORM()                                                             \
  do {                                                                       \
    float mx = fmaxf(fmaxf(fmaxf(b0, b1v), fmaxf(b2v, b3v)), b4v);           \
    int e = (int)((__float_as_uint(mx) >> 23) & 255) - 126;                  \
    e = (act && mx > 0.f) ? e : 0;                                           \
    b0 = ldexpf(b0, -e); b1v = ldexpf(b1v, -e); b2v = ldexpf(b2v, -e);       \
    b3v = ldexpf(b3v, -e); b4v = ldexpf(b4v, -e);                            \
    eps += e;                                                                \
  } while (0)

#define PAIR(C0, C1, N0, N1, P0, P1, DOREN)                                  \
  do {                                                                       \
    ksum += C0; ksum += C1;                                                  \
    if (!act) eps = eL;                                                      \
    bool inc = (g != 0) &&                                                   \
               ((m1 != 0.f) || (m2 != 0.f) || (m3 != 0.f));                  \
    int d = inc ? (eL - eps) : 0;                                            \
    if (__builtin_expect(d > 24, 0)) {            /* raise own frame */      \
      b0 = ldexpf(b0, -d); b1v = ldexpf(b1v, -d); b2v = ldexpf(b2v, -d);     \
      b3v = ldexpf(b3v, -d); b4v = ldexpf(b4v, -d);                          \
      eps += d;                                   /* m stay in frame eL */   \
    } else {                                                                 \
      m1 = ldexpf(m1, d); m2 = ldexpf(m2, d); m3 = ldexpf(m3, d);            \
    }                                                                        \
    act = act || (m1 != 0.f) || (m2 != 0.f) || (m3 != 0.f);                  \
    /* sub-step 1 (in-place top-down; uses old lower states) */              \
    b4v = (b4v + b3v) * es0v;                                                \
    b3v = (b3v + b2v + (sk3 ? b1v : 0.f)) * eBa;                             \
    b2v = (b2v + b1v) * es0v;                                                \
    b1v = (b1v + b0 + (sk1 ? m1 : 0.f)) * eAa;                               \
    b0  = (b0 + m1) * es0v;                                                  \
    m1  = (m1 + m2 + (skm1 ? m3 : 0.f)) * em1a;                              \
    /* sub-step 2 */                                                         \
    b4v = (b4v + b3v) * es1v;                                                \
    b3v = (b3v + b2v + (sk3 ? b1v : 0.f)) * eBb;                             \
    b2v = (b2v + b1v) * es1v;                                                \
    b1v = (b1v + b0 + (sk1 ? m1 : 0.f)) * eAb;                               \
    b0  = (b0 + m1) * es1v;                                                  \
    C0 = ROWL(P0); C1 = ROWL(P1);                 /* refill ring slots */    \
    if (DOREN) RENORM();                                                     \
    /* gathers for next pair (in-order DS: partial waits possible) */        \
    es0v = rdlane(N0, 57);                                                   \
    eAa = bperm(N0, adA); eBa = bperm(N0, adB); em1a = bperm(N0, adm1);      \
    es1v = rdlane(N1, 57);                                                   \
    eAb = bperm(N1, adA); eBb = bperm(N1, adB);                              \
    /* boundary: states 4g-3..4g-1 + frame */                                \
    m3 = __shfl_up(b1v, 1); m2 = __shfl_up(b2v, 1); m1 = __shfl_up(b3v, 1);  \
    eL = __shfl_up(eps, 1);                                                  \
    if (wid == 0 && lane == 63) {                 /* cross-wave hand-off */  \
      float* sl = bnd + pp * 8;                                              \
      sl[0] = b1v; sl[1] = b2v; sl[2] = b3v; ((int*)sl)[3] = eps;            \
    }                                                                        \
    __syncthreads();                                                         \
    if (wid == 1 && lane == 0) {                                             \
      const float* sl = bnd + pp * 8;                                        \
      m3 = sl[0]; m2 = sl[1]; m1 = sl[2]; eL = ((const int*)sl)[3];          \
    }                                                                        \
    if (g == 0) { m1 = 0.f; m2 = 0.f; m3 = 0.f; }                            \
    pp ^= 1;                                                                 \
  } while (0)

  int t0 = 1;
  for (; t0 + 8 <= len; t0 += 8) {
    int tmax = t0 + 15;
    if (tmax > len - 1) tmax = len - 1;
    WAITC(tmax >> 7);                            // gate ring refills t0+8..+15
    PAIR(rr0, rr1, rr2, rr3, t0 + 8,  t0 + 9,  false);
    PAIR(rr2, rr3, rr4, rr5, t0 + 10, t0 + 11, false);
    PAIR(rr4, rr5, rr6, rr7, t0 + 12, t0 + 13, false);
    PAIR(rr6, rr7, rr0, rr1, t0 + 14, t0 + 15, true);  // t0+7 == 0 mod 8
  }

  WAITC((len - 1) >> 7);                         // cover tail reads

  // tail: <= 7 single steps (m1/eL re-exchanged each step)
  for (int t = t0; t < len; ++t) {
    float cur = ROWL(t);
    float esv = rdlane(cur, 57);
    float eAv = bperm(cur, adA), eBv = bperm(cur, adB);
    ksum += cur;
    if (!act) eps = eL;
    bool inc = (g != 0) && (m1 != 0.f);
    int d = inc ? (eL - eps) : 0;
    float m1s;
    if (__builtin_expect(d > 24, 0)) {
      b0 = ldexpf(b0, -d); b1v = ldexpf(b1v, -d); b2v = ldexpf(b2v, -d);
      b3v = ldexpf(b3v, -d); b4v = ldexpf(b4v, -d);
      eps += d; m1s = m1;
    } else {
      m1s = inc ? ldexpf(m1, d) : 0.f;
    }
    act = act || (m1s != 0.f);
    b4v = (b4v + b3v) * esv;
    b3v = (b3v + b2v + (sk3 ? b1v : 0.f)) * eBv;
    b2v = (b2v + b1v) * esv;
    b1v = (b1v + b0 + (sk1 ? m1s : 0.f)) * eAv;
    b0  = (b0 + m1s) * esv;
    if ((t & 7) == 0) RENORM();
    m1 = __shfl_up(b3v, 1);
    eL = __shfl_up(eps, 1);
    if (wid == 0 && lane == 63) {
      float* sl = bnd + pp * 8;
      sl[2] = b3v; ((int*)sl)[3] = eps;
    }
    __syncthreads();
    if (wid == 1 && lane == 0) {
      const float* sl = bnd + pp * 8;
      m1 = sl[2]; eL = ((const int*)sl)[3];
    }
    if (g == 0) m1 = 0.f;
    pp ^= 1;
  }

  // final reduce across the 2 waves via LDS
  int last = 2 * tl;
  int gx = last >> 2, jx = last & 3;
  if (gx > 127) { gx = 127; jx = last - 508; }   // state 512 -> lane127 b4
  int gy = (last - 1) >> 2, jy = (last - 1) & 3;
  float vx = pick5(jx, b0, b1v, b2v, b3v, b4v);
  float vy = pick5(jy, b0, b1v, b2v, b3v, b4v);
  if (g == gx) { fin[0] = vx; ((int*)fin)[1] = eps; }
  if (g == gy) { fin[2] = vy; ((int*)fin)[3] = eps; }
  __syncthreads();
  if (g == 0) {
    float k56 = rdlane(ksum, 56);                // wave0 holds full ksum
    float sx = fin[0]; int ex = ((const int*)fin)[1];
    float sy = fin[2]; int ey = ((const int*)fin)[3];
    int em = (ex > ey) ? ex : ey;
    float v = ldexpf(sx, ex - em) + ldexpf(sy, ey - em);
    float score = logf(v) + (float)em * LN2f - k56;
    partial[n] = -score / (float)tl;
  }
#undef WAITC
#undef ROWL
#undef RENORM
#undef PAIR
}

// ---------------------------------------------------------------------------
// Kernel 3: mean over batch
// ---------------------------------------------------------------------------
__global__ void reduce_mean(const float* __restrict__ partial,
                            float* __restrict__ out, int B) {
  float v = 0.f;
  for (int i = threadIdx.x; i < B; i += 64) v += partial[i];
  #pragma unroll
  for (int off = 32; off > 0; off >>= 1) v += __shfl_down(v, off, 64);
  if (threadIdx.x == 0) out[0] = v / (float)B;
}

extern "C" void kernel_launch(void* const* d_in, const int* in_sizes, int n_in,
                              void* d_out, int out_size, void* d_ws, size_t ws_size,
                              hipStream_t stream) {
  const float* feat = (const float*)d_in[0];
  const float* W = (const float*)d_in[1];
  const float* bias = (const float*)d_in[2];
  const int* targets = (const int*)d_in[3];
  const int* in_len = (const int*)d_in[4];
  const int* tgt_len = (const int*)d_in[5];
  float* out = (float*)d_out;

  const int V = in_sizes[2];
  const int D = in_sizes[1] / V;
  const int B = in_sizes[4];
  const int T = in_sizes[0] / (B * D);
  const int S = in_sizes[3] / B;
  const int nrows = B * T;

  float* pt = (float*)d_ws;                         // nrows*64 fp32 (32 MB)
  float* partial = pt + (size_t)nrows * 64;         // B fp32
  short* Wb = (short*)(partial + B);                // 64*D bf16
  const int CPB = (T + 127) / 128;                  // time-chunks per batch
  int* flags = (int*)((char*)Wb + (size_t)64 * D * sizeof(short));  // B*CPB

  conv_w<<<(64 * D + 255) / 256, 256, 0, stream>>>(W, Wb, V, D,
                                                   flags, B * CPB);

  // grid = B consumers + 128 persistent producers (c-major wavefront:
  // 4 tiles each; chunks 0-3 ready after round 0 while DP streams behind).
  const int NTILES = B * CPB;
  int NPROD = 128;
  if (NPROD > NTILES) NPROD = NTILES;
  fused_gemm_star<<<dim3(B + NPROD), 256, 0, stream>>>(
      feat, Wb, bias, pt, flags, targets, in_len, tgt_len, partial,
      nrows, D, V, T, S, B, CPB);

  reduce_mean<<<1, 64, 0, stream>>>(partial, out, B);
}